// Round 1
// baseline (55094.427 us; speedup 1.0000x reference)
//
#include <hip/hip_runtime.h>
#include <math.h>

#define CKCH 512
#define NLEV 10
#define NBATCH 4
#define NSEQ 1024
#define TWO_PI_F 6.2831853071795864769f
#define INV_SQRT2 0.70710678118654752440f

// ---------------------------------------------------------------------------
// block-wide stats reduction (256 threads = 4 waves of 64), accumulates
// sum and sum-of-squares into a 2-double stats slot via fp64 atomics.
// ---------------------------------------------------------------------------
__device__ __forceinline__ void block_stats_256(float s, float s2, double* st, int tid) {
  #pragma unroll
  for (int off = 32; off > 0; off >>= 1) {
    s  += __shfl_down(s, off);
    s2 += __shfl_down(s2, off);
  }
  __shared__ float sh1[4], sh2[4];
  int w = tid >> 6;
  if ((tid & 63) == 0) { sh1[w] = s; sh2[w] = s2; }
  __syncthreads();
  if (tid == 0) {
    float a = sh1[0] + sh1[1] + sh1[2] + sh1[3];
    float b = sh2[0] + sh2[1] + sh2[2] + sh2[3];
    atomicAdd(st,     (double)a);
    atomicAdd(st + 1, (double)b);
  }
}

// ---------------------------------------------------------------------------
// L1 projection fused with transpose: out[b][k][t] = sum_d values[b,t,d]*W[k,d] + bias[k]
// out is the (512, 1024) row-major per-batch buffer (wavelet cA0).
// ---------------------------------------------------------------------------
#define TT1 8
__global__ __launch_bounds__(256) void k_l1t(const float* __restrict__ vals,
                                             const float* __restrict__ w,
                                             const float* __restrict__ bias,
                                             float* __restrict__ out) {
  __shared__ float sh[TT1][256];
  int b = blockIdx.z;
  int t0 = blockIdx.x * TT1;
  int tid = threadIdx.x;
  for (int i = tid; i < TT1 * 256; i += 256) {
    int tt = i >> 8, d = i & 255;
    sh[tt][d] = vals[((size_t)(b * NSEQ + t0 + tt)) * 256 + d];
  }
  __syncthreads();
  for (int k = tid; k < CKCH; k += 256) {
    float acc[TT1];
    #pragma unroll
    for (int tt = 0; tt < TT1; ++tt) acc[tt] = 0.f;
    const float* wr = w + (size_t)k * 256;
    for (int d = 0; d < 256; ++d) {
      float wv = wr[d];
      #pragma unroll
      for (int tt = 0; tt < TT1; ++tt) acc[tt] += sh[tt][d] * wv;
    }
    float bv = bias[k];
    #pragma unroll
    for (int tt = 0; tt < TT1; ++tt)
      out[(size_t)b * CKCH * NSEQ + (size_t)k * NSEQ + (t0 + tt)] = acc[tt] + bv;
  }
}

// ---------------------------------------------------------------------------
// stride-2 "same"-padded conv: Y[b][o][t] = sum_{i,f} X[b][i][2t+f-3]*W[o][i][f] + bias[o]
// X flat per-batch viewed as (512, L) row-major. Y is (512, L/2).
// ---------------------------------------------------------------------------
__global__ __launch_bounds__(256) void k_conv2(const float* __restrict__ X, size_t xbs,
                                               const float* __restrict__ W,
                                               const float* __restrict__ bias,
                                               float* __restrict__ Y, size_t ybs, int L) {
  int Lh = L >> 1;
  int b = blockIdx.z;
  int o = blockIdx.y * blockDim.y + threadIdx.y;
  int t = blockIdx.x * blockDim.x + threadIdx.x;
  if (t >= Lh) return;
  const float* Xb = X + (size_t)b * xbs;
  const float* wo = W + (size_t)o * CKCH * 7;
  int p0 = 2 * t - 3;
  float acc = 0.f;
  if (p0 >= 0 && p0 + 6 < L) {
    for (int i = 0; i < CKCH; ++i) {
      const float* xr = Xb + (size_t)i * L + p0;
      const float* wr = wo + i * 7;
      #pragma unroll
      for (int f = 0; f < 7; ++f) acc += xr[f] * wr[f];
    }
  } else {
    for (int i = 0; i < CKCH; ++i) {
      const float* xr = Xb + (size_t)i * L;
      const float* wr = wo + i * 7;
      #pragma unroll
      for (int f = 0; f < 7; ++f) {
        int p = p0 + f;
        if (p >= 0 && p < L) acc += xr[p] * wr[f];
      }
    }
  }
  Y[(size_t)b * ybs + (size_t)o * Lh + t] = acc + bias[o];
}

// ---------------------------------------------------------------------------
// Truncated forward DFT of the scrambled view xr[k,m] = H_flat[m*512+k]:
// xf[b,k,x] = sum_m xr * e^{-2*pi*i*x*m/Lh}, x < l <= 16.  Lh is a power of 2.
// ---------------------------------------------------------------------------
__global__ __launch_bounds__(64) void k_dft(const float* __restrict__ H, size_t hbs,
                                            float* __restrict__ xfr, float* __restrict__ xfi,
                                            int Lh) {
  int b = blockIdx.z, x = blockIdx.y;
  int k = blockIdx.x * 64 + threadIdx.x;
  const float* Hb = H + (size_t)b * hbs;
  float invL = 1.0f / (float)Lh;
  int mask = Lh - 1;
  float ar = 0.f, ai = 0.f;
  for (int m = 0; m < Lh; ++m) {
    float v = Hb[(size_t)m * CKCH + k];
    int p = (x * m) & mask;
    float s, c;
    sincosf(-TWO_PI_F * (float)p * invL, &s, &c);
    ar += v * c;
    ai += v * s;
  }
  xfr[((size_t)b * CKCH + k) * 16 + x] = ar;
  xfi[((size_t)b * CKCH + k) * 16 + x] = ai;
}

// ---------------------------------------------------------------------------
// Per-mode complex channel mixing: out[b,o,x] = sum_i xf[b,i,x] * (wr+j*wi)[i,o,x]
// ---------------------------------------------------------------------------
__global__ __launch_bounds__(256) void k_einsum(const float* __restrict__ xfr,
                                                const float* __restrict__ xfi,
                                                const float* __restrict__ wr,
                                                const float* __restrict__ wi,
                                                float* __restrict__ outr,
                                                float* __restrict__ outi, int l) {
  int gid = blockIdx.x * 256 + threadIdx.x;
  int o = gid >> 4, x = gid & 15;
  if (x >= l) return;
  float ar[NBATCH] = {0, 0, 0, 0}, ai[NBATCH] = {0, 0, 0, 0};
  for (int i = 0; i < CKCH; ++i) {
    float wre = wr[((size_t)i * CKCH + o) * 16 + x];
    float wim = wi[((size_t)i * CKCH + o) * 16 + x];
    #pragma unroll
    for (int b = 0; b < NBATCH; ++b) {
      float xre = xfr[((size_t)b * CKCH + i) * 16 + x];
      float xim = xfi[((size_t)b * CKCH + i) * 16 + x];
      ar[b] += xre * wre - xim * wim;
      ai[b] += xre * wim + xim * wre;
    }
  }
  #pragma unroll
  for (int b = 0; b < NBATCH; ++b) {
    outr[((size_t)b * CKCH + o) * 16 + x] = ar[b];
    outi[((size_t)b * CKCH + o) * 16 + x] = ai[b];
  }
}

// ---------------------------------------------------------------------------
// Truncated irfft of padded spectrum + layout [t*512+k] write + global stats.
// numpy irfft semantics: Im ignored at DC and (if present) Nyquist (sin==0 there).
// ---------------------------------------------------------------------------
__global__ __launch_bounds__(256) void k_irfft(const float* __restrict__ outr,
                                               const float* __restrict__ outi,
                                               float* __restrict__ Y, size_t ybs,
                                               double* __restrict__ st, int Lh, int l) {
  int b = blockIdx.z, t = blockIdx.y;
  int k = blockIdx.x * 256 + threadIdx.x;
  int mask = Lh - 1;
  float invL = 1.0f / (float)Lh;
  float acc = 0.f;
  for (int x = 0; x < l; ++x) {
    float re = outr[((size_t)b * CKCH + k) * 16 + x];
    float im = outi[((size_t)b * CKCH + k) * 16 + x];
    float coef = (x == 0 || 2 * x == Lh) ? 1.f : 2.f;
    int p = (x * t) & mask;
    float s, c;
    sincosf(TWO_PI_F * (float)p * invL, &s, &c);
    acc += coef * (re * c - im * s);
  }
  float y = acc * invL;
  Y[(size_t)b * ybs + (size_t)t * CKCH + k] = y;
  block_stats_256(y, y * y, st, threadIdx.x);
}

// ---------------------------------------------------------------------------
// (v - mean)/std (subMean=1) or v/std (subMean=0); std with ddof=1 from stats.
// ---------------------------------------------------------------------------
__global__ __launch_bounds__(256) void k_norm(float* __restrict__ Y, size_t ybs,
                                              const double* __restrict__ st,
                                              long ntot, int nbatch, int subMean) {
  long idx = (long)blockIdx.x * 256 + threadIdx.x;
  if (idx >= ntot) return;
  double s1 = st[0], s2 = st[1];
  double mean = s1 / (double)ntot;
  double var = (s2 - s1 * mean) / (double)(ntot - 1);
  float rstd = (float)(1.0 / sqrt(var));
  float mu = subMean ? (float)mean : 0.f;
  int b = (int)(idx / nbatch);
  long r = idx % nbatch;
  float* p = Y + (size_t)b * ybs + r;
  *p = (*p - mu) * rstd;
}

// ---------------------------------------------------------------------------
// Reconstruction step: s[o,t] = conv1(upsample(cA), WA) + conv1(upsample(cD), WD) (+biases)
// upsample: X[i,tau] = U[i, tau>>1]; stride-1 conv, "same" pad. Stats for /std.
// ---------------------------------------------------------------------------
__global__ __launch_bounds__(256) void k_conv_rec(const float* __restrict__ UA, size_t abs_,
                                                  const float* __restrict__ UD, size_t dbs,
                                                  const float* __restrict__ WA,
                                                  const float* __restrict__ bA,
                                                  const float* __restrict__ WD,
                                                  const float* __restrict__ bD,
                                                  float* __restrict__ S, size_t sbs,
                                                  double* __restrict__ st, int Ld) {
  int L2 = Ld * 2;
  int b = blockIdx.z;
  int o = blockIdx.y * blockDim.y + threadIdx.y;
  int t = blockIdx.x * blockDim.x + threadIdx.x;
  bool valid = (t < L2);
  float acc = 0.f;
  if (valid) {
    const float* Ua = UA + (size_t)b * abs_;
    const float* Ud = UD + (size_t)b * dbs;
    const float* wa = WA + (size_t)o * CKCH * 7;
    const float* wd = WD + (size_t)o * CKCH * 7;
    int p0 = t - 3;
    for (int i = 0; i < CKCH; ++i) {
      const float* ua = Ua + (size_t)i * Ld;
      const float* ud = Ud + (size_t)i * Ld;
      #pragma unroll
      for (int f = 0; f < 7; ++f) {
        int p = p0 + f;
        if (p >= 0 && p < L2) {
          int q = p >> 1;
          acc += ua[q] * wa[i * 7 + f] + ud[q] * wd[i * 7 + f];
        }
      }
    }
    acc += bA[o] + bD[o];
    S[(size_t)b * sbs + (size_t)o * L2 + t] = acc;
  }
  float v = valid ? acc : 0.f;
  block_stats_256(v, v * v, st, threadIdx.x + threadIdx.y * blockDim.x);
}

// ---------------------------------------------------------------------------
// Between-block permute: out[b][k*1024+t] = relu(in[b][t*512+k]) * (1/sqrt(2))
// ---------------------------------------------------------------------------
__global__ __launch_bounds__(256) void k_permute_relu(const float* __restrict__ in,
                                                      float* __restrict__ out) {
  long idx = (long)blockIdx.x * 256 + threadIdx.x;
  const long total = (long)NBATCH * CKCH * NSEQ;
  if (idx >= total) return;
  int b = (int)(idx / (CKCH * NSEQ));
  int r = (int)(idx % (CKCH * NSEQ));
  int k = r / NSEQ, t = r % NSEQ;
  float v = in[(size_t)b * CKCH * NSEQ + (size_t)t * CKCH + k];
  out[idx] = fmaxf(v, 0.f) * INV_SQRT2;
}

// ---------------------------------------------------------------------------
// Final L2 projection with fused relu+1/sqrt2 on the flat (m*512+k) view:
// out[b,m,o] = sum_k relu(F[m*512+k]/sqrt2) * W[o,k] + bias[o]
// ---------------------------------------------------------------------------
#define TT2 8
__global__ __launch_bounds__(256) void k_l2(const float* __restrict__ Vf,
                                            const float* __restrict__ w,
                                            const float* __restrict__ bias,
                                            float* __restrict__ out) {
  __shared__ float sh[TT2][CKCH];
  int b = blockIdx.z;
  int m0 = blockIdx.x * TT2;
  int tid = threadIdx.x;
  for (int i = tid; i < TT2 * CKCH; i += 256) {
    int tt = i >> 9, k = i & 511;
    float v = Vf[(size_t)b * CKCH * NSEQ + (size_t)(m0 + tt) * CKCH + k];
    sh[tt][k] = fmaxf(v, 0.f) * INV_SQRT2;
  }
  __syncthreads();
  int o = tid;  // 256 threads -> 256 output channels
  float acc[TT2];
  #pragma unroll
  for (int tt = 0; tt < TT2; ++tt) acc[tt] = 0.f;
  const float* wo = w + (size_t)o * CKCH;
  for (int k = 0; k < CKCH; ++k) {
    float wv = wo[k];
    #pragma unroll
    for (int tt = 0; tt < TT2; ++tt) acc[tt] += sh[tt][k] * wv;
  }
  float bv = bias[o];
  #pragma unroll
  for (int tt = 0; tt < TT2; ++tt)
    out[((size_t)b * NSEQ + m0 + tt) * 256 + o] = acc[tt] + bv;
}

// ---------------------------------------------------------------------------
extern "C" void kernel_launch(void* const* d_in, const int* in_sizes, int n_in,
                              void* d_out, int out_size, void* d_ws, size_t ws_size,
                              hipStream_t stream) {
  const float* values  = (const float*)d_in[2];
  const float* L1w     = (const float*)d_in[4];
  const float* L1b     = (const float*)d_in[5];
  const float* L2w     = (const float*)d_in[6];
  const float* L2b     = (const float*)d_in[7];
  const float* ec_hp_w = (const float*)d_in[8];
  const float* ec_hp_b = (const float*)d_in[9];
  const float* ec_lp_w = (const float*)d_in[10];
  const float* ec_lp_b = (const float*)d_in[11];
  const float* hp_wr   = (const float*)d_in[12];
  const float* hp_wi   = (const float*)d_in[13];
  const float* lp_wr   = (const float*)d_in[14];
  const float* lp_wi   = (const float*)d_in[15];
  const float* rc_lp_w = (const float*)d_in[16];
  const float* rc_lp_b = (const float*)d_in[17];
  const float* rc_hp_w = (const float*)d_in[18];
  const float* rc_hp_b = (const float*)d_in[19];

  double* stats = (double*)d_ws;
  float* base = (float*)((char*)d_ws + 4096);
  const size_t AB = (size_t)CKCH * NSEQ;   // 524288 per-batch ping/pong
  const size_t CB = (size_t)CKCH * CKCH;   // 262144 conv-out scratch
  const size_t XB = (size_t)CKCH * 16;     // mode buffers
  const size_t DB = (size_t)CKCH * 1023;   // all detail levels

  float* A   = base;
  float* Bb  = A   + (size_t)NBATCH * AB;
  float* C1  = Bb  + (size_t)NBATCH * AB;
  float* XFr = C1  + (size_t)NBATCH * CB;
  float* XFi = XFr + (size_t)NBATCH * XB;
  float* OMr = XFi + (size_t)NBATCH * XB;
  float* OMi = OMr + (size_t)NBATCH * XB;
  float* Dd  = OMi + (size_t)NBATCH * XB;  // ~30 MB total ws use

  hipMemsetAsync(stats, 0, 256 * sizeof(double), stream);

  k_l1t<<<dim3(NSEQ / TT1, 1, NBATCH), 256, 0, stream>>>(values, L1w, L1b, A);

  float* cur = A;
  float* nxt = Bb;
  int slot = 0;

  for (int blk = 0; blk < 2; ++blk) {
    const float* ehw = ec_hp_w + (size_t)blk * CKCH * CKCH * 7;
    const float* ehb = ec_hp_b + (size_t)blk * CKCH;
    const float* elw = ec_lp_w + (size_t)blk * CKCH * CKCH * 7;
    const float* elb = ec_lp_b + (size_t)blk * CKCH;
    const float* hwr = hp_wr + (size_t)blk * CKCH * CKCH * 16;
    const float* hwi = hp_wi + (size_t)blk * CKCH * CKCH * 16;
    const float* lwr = lp_wr + (size_t)blk * CKCH * CKCH * 16;
    const float* lwi = lp_wi + (size_t)blk * CKCH * CKCH * 16;
    const float* rlw = rc_lp_w + (size_t)blk * CKCH * CKCH * 7;
    const float* rlb = rc_lp_b + (size_t)blk * CKCH;
    const float* rhw = rc_hp_w + (size_t)blk * CKCH * CKCH * 7;
    const float* rhb = rc_hp_b + (size_t)blk * CKCH;

    int L = NSEQ;
    size_t doff = 0;
    for (int lvl = 0; lvl < NLEV; ++lvl) {
      int Lh = L >> 1;
      int l = (Lh / 2 + 1 < 16) ? (Lh / 2 + 1) : 16;
      dim3 cgrid((Lh + 63) / 64, CKCH / 4, NBATCH), cblk(64, 4);
      long tot = (long)NBATCH * CKCH * Lh;

      // high-pass branch -> detail buffer
      k_conv2<<<cgrid, cblk, 0, stream>>>(cur, AB, ehw, ehb, C1, CB, L);
      k_dft<<<dim3(CKCH / 64, l, NBATCH), 64, 0, stream>>>(C1, CB, XFr, XFi, Lh);
      k_einsum<<<dim3(CKCH * 16 / 256), 256, 0, stream>>>(XFr, XFi, hwr, hwi, OMr, OMi, l);
      {
        double* st = stats + 2 * slot; slot++;
        k_irfft<<<dim3(CKCH / 256, Lh, NBATCH), 256, 0, stream>>>(OMr, OMi, Dd + doff, DB, st, Lh, l);
        k_norm<<<dim3((unsigned)((tot + 255) / 256)), 256, 0, stream>>>(Dd + doff, DB, st, tot, CKCH * Lh, 1);
      }
      // low-pass branch -> next approximation
      k_conv2<<<cgrid, cblk, 0, stream>>>(cur, AB, elw, elb, C1, CB, L);
      k_dft<<<dim3(CKCH / 64, l, NBATCH), 64, 0, stream>>>(C1, CB, XFr, XFi, Lh);
      k_einsum<<<dim3(CKCH * 16 / 256), 256, 0, stream>>>(XFr, XFi, lwr, lwi, OMr, OMi, l);
      {
        double* st = stats + 2 * slot; slot++;
        k_irfft<<<dim3(CKCH / 256, Lh, NBATCH), 256, 0, stream>>>(OMr, OMi, nxt, AB, st, Lh, l);
        k_norm<<<dim3((unsigned)((tot + 255) / 256)), 256, 0, stream>>>(nxt, AB, st, tot, CKCH * Lh, 1);
      }
      float* tmp = cur; cur = nxt; nxt = tmp;
      doff += (size_t)CKCH * Lh;
      L = Lh;
    }

    // reconstruction
    int Ld = 1;
    for (int lv = 0; lv < NLEV; ++lv) {
      int lvlD = NLEV - 1 - lv;
      size_t od = (size_t)CKCH * (size_t)(1024 - (1024 >> lvlD));
      int L2 = 2 * Ld;
      double* st = stats + 2 * slot; slot++;
      dim3 rgrid((L2 + 63) / 64, CKCH / 4, NBATCH), rblk(64, 4);
      k_conv_rec<<<rgrid, rblk, 0, stream>>>(cur, AB, Dd + od, DB, rlw, rlb, rhw, rhb, nxt, AB, st, Ld);
      long tot = (long)NBATCH * CKCH * L2;
      k_norm<<<dim3((unsigned)((tot + 255) / 256)), 256, 0, stream>>>(nxt, AB, st, tot, CKCH * L2, 0);
      float* tmp = cur; cur = nxt; nxt = tmp;
      Ld = L2;
    }

    if (blk == 0) {
      long tot = (long)NBATCH * CKCH * NSEQ;
      k_permute_relu<<<dim3((unsigned)((tot + 255) / 256)), 256, 0, stream>>>(cur, nxt);
      float* tmp = cur; cur = nxt; nxt = tmp;
    }
  }

  k_l2<<<dim3(NSEQ / TT2, 1, NBATCH), 256, 0, stream>>>(cur, L2w, L2b, (float*)d_out);
}

// Round 3
// 28761.575 us; speedup vs baseline: 1.9156x; 1.9156x over previous
//
#include <hip/hip_runtime.h>
#include <math.h>

#define CKCH 512
#define NLEV 10
#define NBATCH 4
#define NSEQ 1024
#define TWO_PI_F 6.2831853071795864769f
#define INV_SQRT2 0.70710678118654752440f
#define IC 8

// ---------------------------------------------------------------------------
// global-affine from fp64 stats slot: x_norm = x*r + madj
// ---------------------------------------------------------------------------
__device__ __forceinline__ void get_affine(const double* st, long ntot, int subMean,
                                           float& r, float& madj) {
  r = 1.f; madj = 0.f;
  if (!st) return;
  double s1 = st[0], s2 = st[1];
  double mean = s1 / (double)ntot;
  double var = (s2 - s1 * mean) / (double)(ntot - 1);
  double rs = 1.0 / sqrt(var);
  r = (float)rs;
  madj = subMean ? (float)(-mean * rs) : 0.f;
}

template<int NTHR>
__device__ __forceinline__ void block_stats(float s, float s2, double* st, int tid) {
  if constexpr (NTHR <= 64) {
    #pragma unroll
    for (int off = NTHR / 2; off > 0; off >>= 1) {
      s += __shfl_down(s, off);
      s2 += __shfl_down(s2, off);
    }
    if (tid == 0) { atomicAdd(st, (double)s); atomicAdd(st + 1, (double)s2); }
  } else {
    #pragma unroll
    for (int off = 32; off > 0; off >>= 1) {
      s += __shfl_down(s, off);
      s2 += __shfl_down(s2, off);
    }
    __shared__ float sh1[NTHR / 64], sh2[NTHR / 64];
    int w = tid >> 6;
    if ((tid & 63) == 0) { sh1[w] = s; sh2[w] = s2; }
    __syncthreads();
    if (tid == 0) {
      float a = 0.f, b = 0.f;
      #pragma unroll
      for (int i = 0; i < NTHR / 64; ++i) { a += sh1[i]; b += sh2[i]; }
      atomicAdd(st, (double)a); atomicAdd(st + 1, (double)b);
    }
  }
}

// ---------------------------------------------------------------------------
// L1 projection fused with transpose: out[b][k][t] = sum_d vals[b,t,d]*W[k,d]+b[k]
// ---------------------------------------------------------------------------
#define TT1 8
__global__ __launch_bounds__(256) void k_l1t(const float* __restrict__ vals,
                                             const float* __restrict__ w,
                                             const float* __restrict__ bias,
                                             float* __restrict__ out) {
  __shared__ float sh[TT1][256];
  int b = blockIdx.z;
  int t0 = blockIdx.x * TT1;
  int tid = threadIdx.x;
  for (int i = tid; i < TT1 * 256; i += 256) {
    int tt = i >> 8, d = i & 255;
    sh[tt][d] = vals[((size_t)(b * NSEQ + t0 + tt)) * 256 + d];
  }
  __syncthreads();
  for (int k = tid; k < CKCH; k += 256) {
    float acc[TT1];
    #pragma unroll
    for (int tt = 0; tt < TT1; ++tt) acc[tt] = 0.f;
    const float* wr = w + (size_t)k * 256;
    for (int d = 0; d < 256; ++d) {
      float wv = wr[d];
      #pragma unroll
      for (int tt = 0; tt < TT1; ++tt) acc[tt] += sh[tt][d] * wv;
    }
    float bv = bias[k];
    #pragma unroll
    for (int tt = 0; tt < TT1; ++tt)
      out[(size_t)b * CKCH * NSEQ + (size_t)k * NSEQ + (t0 + tt)] = acc[tt] + bv;
  }
}

// ---------------------------------------------------------------------------
// Tiled stride-2 conv, fused input affine. Thread tile 4o x 4t (contiguous t).
// block (TT/4, 8), o-tile 32 per block.
// ---------------------------------------------------------------------------
template<int TT>
__global__ __launch_bounds__((TT / 4) * 8) void k_conv2_t(
    const float* __restrict__ X, size_t xbs,
    const double* __restrict__ st, long ntot, int subMean,
    const float* __restrict__ W, const float* __restrict__ bias,
    float* __restrict__ Y, size_t ybs, int L) {
  constexpr int SP = 2 * TT + 8;
  constexpr int NTHR = (TT / 4) * 8;
  __shared__ float Xs[IC][SP];
  __shared__ float Ws[IC][32][8];
  int tx = threadIdx.x, ty = threadIdx.y;
  int tid = ty * (TT / 4) + tx;
  int b = blockIdx.z;
  int t0 = blockIdx.x * TT;
  int o0 = blockIdx.y * 32;
  int Lh = L >> 1;
  float r, madj;
  get_affine(st, ntot, subMean, r, madj);
  const float* Xb = X + (size_t)b * xbs;
  int pbase = 2 * t0 - 3;
  float acc[4][4];
  #pragma unroll
  for (int i = 0; i < 4; ++i)
    #pragma unroll
    for (int j = 0; j < 4; ++j) acc[i][j] = 0.f;

  for (int ic = 0; ic < CKCH / IC; ++ic) {
    int i0 = ic * IC;
    for (int idx = tid; idx < IC * (2 * TT + 6); idx += NTHR) {
      int ii = idx / (2 * TT + 6), pp = idx % (2 * TT + 6);
      int p = pbase + pp;
      float v = 0.f;
      if (p >= 0 && p < L) v = fmaf(Xb[(size_t)(i0 + ii) * L + p], r, madj);
      Xs[ii][pp] = v;
    }
    for (int idx = tid; idx < 32 * IC * 7; idx += NTHR) {
      int o = idx / (IC * 7);
      int rr = idx % (IC * 7);
      int ii = rr / 7, f = rr % 7;
      Ws[ii][o][f] = W[((size_t)(o0 + o) * CKCH + (i0 + ii)) * 7 + f];
    }
    __syncthreads();
    #pragma unroll
    for (int ii = 0; ii < IC; ++ii) {
      float xv[16];
      #pragma unroll
      for (int u = 0; u < 4; ++u)
        *(float4*)&xv[4 * u] = *(const float4*)&Xs[ii][8 * tx + 4 * u];
      #pragma unroll
      for (int oo = 0; oo < 4; ++oo) {
        float wv[8];
        *(float4*)&wv[0] = *(const float4*)&Ws[ii][ty + 8 * oo][0];
        *(float4*)&wv[4] = *(const float4*)&Ws[ii][ty + 8 * oo][4];
        #pragma unroll
        for (int tt = 0; tt < 4; ++tt)
          #pragma unroll
          for (int f = 0; f < 7; ++f)
            acc[oo][tt] = fmaf(xv[2 * tt + f], wv[f], acc[oo][tt]);
      }
    }
    __syncthreads();
  }
  float* Yb = Y + (size_t)b * ybs;
  #pragma unroll
  for (int oo = 0; oo < 4; ++oo) {
    int o = o0 + ty + 8 * oo;
    float bv = bias[o];
    float4 v = make_float4(acc[oo][0] + bv, acc[oo][1] + bv,
                           acc[oo][2] + bv, acc[oo][3] + bv);
    *(float4*)&Yb[(size_t)o * Lh + t0 + 4 * tx] = v;
  }
}

// wave-per-output variant for tiny levels (Lh <= 8)
__global__ __launch_bounds__(256) void k_conv2_w(
    const float* __restrict__ X, size_t xbs,
    const double* __restrict__ st, long ntot, int subMean,
    const float* __restrict__ W, const float* __restrict__ bias,
    float* __restrict__ Y, size_t ybs, int L) {
  int Lh = L >> 1;
  int out = blockIdx.x * 4 + (threadIdx.x >> 6);
  int lane = threadIdx.x & 63;
  int total = NBATCH * CKCH * Lh;
  if (out >= total) return;
  int b = out / (CKCH * Lh);
  int rem = out % (CKCH * Lh);
  int o = rem / Lh, t = rem % Lh;
  float r, madj;
  get_affine(st, ntot, subMean, r, madj);
  const float* Xb = X + (size_t)b * xbs;
  const float* wo = W + (size_t)o * CKCH * 7;
  float acc = 0.f;
  for (int j = 0; j < 8; ++j) {
    int i = lane + 64 * j;
    const float* wr = wo + i * 7;
    const float* xr = Xb + (size_t)i * L;
    #pragma unroll
    for (int f = 0; f < 7; ++f) {
      int p = 2 * t + f - 3;
      if (p >= 0 && p < L) acc = fmaf(fmaf(xr[p], r, madj), wr[f], acc);
    }
  }
  #pragma unroll
  for (int off = 32; off > 0; off >>= 1) acc += __shfl_down(acc, off);
  if (lane == 0) Y[(size_t)b * ybs + (size_t)o * Lh + t] = acc + bias[o];
}

// ---------------------------------------------------------------------------
// Tiled reconstruction conv (upsample x2 + two stride-1 convs + sum + stats).
// ---------------------------------------------------------------------------
template<int TT>
__global__ __launch_bounds__((TT / 4) * 8) void k_conv_rec_t(
    const float* __restrict__ A, size_t abs_,
    const double* __restrict__ stA, long ntA, int smA,
    const float* __restrict__ D, size_t dbs,
    const double* __restrict__ stD, long ntD,
    const float* __restrict__ WA, const float* __restrict__ bA,
    const float* __restrict__ WD, const float* __restrict__ bD,
    float* __restrict__ S, size_t sbs,
    double* __restrict__ stOut, int Ld) {
  constexpr int QS = TT / 2 + 8;
  constexpr int NTHR = (TT / 4) * 8;
  __shared__ float As[IC][QS], Ds[IC][QS];
  __shared__ float Was[IC][32][8], Wds[IC][32][8];
  int tx = threadIdx.x, ty = threadIdx.y;
  int tid = ty * (TT / 4) + tx;
  int b = blockIdx.z;
  int t0 = blockIdx.x * TT;
  int o0 = blockIdx.y * 32;
  int L2 = Ld * 2;
  float rA, mA, rD, mD;
  get_affine(stA, ntA, smA, rA, mA);
  get_affine(stD, ntD, 1, rD, mD);
  const float* Ab = A + (size_t)b * abs_;
  const float* Db = D + (size_t)b * dbs;
  int q0 = t0 / 2 - 2;
  float acc[4][4];
  #pragma unroll
  for (int i = 0; i < 4; ++i)
    #pragma unroll
    for (int j = 0; j < 4; ++j) acc[i][j] = 0.f;

  for (int ic = 0; ic < CKCH / IC; ++ic) {
    int i0 = ic * IC;
    for (int idx = tid; idx < IC * (TT / 2 + 4); idx += NTHR) {
      int ii = idx / (TT / 2 + 4), qq = idx % (TT / 2 + 4);
      int q = q0 + qq;
      float va = 0.f, vd = 0.f;
      if (q >= 0 && q < Ld) {
        va = fmaf(Ab[(size_t)(i0 + ii) * Ld + q], rA, mA);
        vd = fmaf(Db[(size_t)(i0 + ii) * Ld + q], rD, mD);
      }
      As[ii][qq] = va;
      Ds[ii][qq] = vd;
    }
    for (int idx = tid; idx < 32 * IC * 7; idx += NTHR) {
      int o = idx / (IC * 7);
      int rr = idx % (IC * 7);
      int ii = rr / 7, f = rr % 7;
      size_t gw = ((size_t)(o0 + o) * CKCH + (i0 + ii)) * 7 + f;
      Was[ii][o][f] = WA[gw];
      Wds[ii][o][f] = WD[gw];
    }
    __syncthreads();
    #pragma unroll
    for (int ii = 0; ii < IC; ++ii) {
      float av[6], dv[6];
      #pragma unroll
      for (int u = 0; u < 3; ++u) {
        *(float2*)&av[2 * u] = *(const float2*)&As[ii][2 * tx + 2 * u];
        *(float2*)&dv[2 * u] = *(const float2*)&Ds[ii][2 * tx + 2 * u];
      }
      #pragma unroll
      for (int oo = 0; oo < 4; ++oo) {
        float wa[8], wd[8];
        *(float4*)&wa[0] = *(const float4*)&Was[ii][ty + 8 * oo][0];
        *(float4*)&wa[4] = *(const float4*)&Was[ii][ty + 8 * oo][4];
        *(float4*)&wd[0] = *(const float4*)&Wds[ii][ty + 8 * oo][0];
        *(float4*)&wd[4] = *(const float4*)&Wds[ii][ty + 8 * oo][4];
        #pragma unroll
        for (int tt = 0; tt < 4; ++tt) {
          #pragma unroll
          for (int f = 0; f < 7; ++f) {
            const int u = ((tt + f - 3) >> 1) + 2;  // compile-time (floor shift)
            acc[oo][tt] = fmaf(av[u], wa[f], acc[oo][tt]);
            acc[oo][tt] = fmaf(dv[u], wd[f], acc[oo][tt]);
          }
        }
      }
    }
    __syncthreads();
  }
  float s = 0.f, s2 = 0.f;
  float* Sb = S + (size_t)b * sbs;
  #pragma unroll
  for (int oo = 0; oo < 4; ++oo) {
    int o = o0 + ty + 8 * oo;
    float bv = bA[o] + bD[o];
    float4 v = make_float4(acc[oo][0] + bv, acc[oo][1] + bv,
                           acc[oo][2] + bv, acc[oo][3] + bv);
    *(float4*)&Sb[(size_t)o * L2 + t0 + 4 * tx] = v;
    s += v.x + v.y + v.z + v.w;
    s2 += v.x * v.x + v.y * v.y + v.z * v.z + v.w * v.w;
  }
  block_stats<NTHR>(s, s2, stOut, tid);
}

__global__ __launch_bounds__(256) void k_conv_rec_w(
    const float* __restrict__ A, size_t abs_,
    const double* __restrict__ stA, long ntA, int smA,
    const float* __restrict__ D, size_t dbs,
    const double* __restrict__ stD, long ntD,
    const float* __restrict__ WA, const float* __restrict__ bA,
    const float* __restrict__ WD, const float* __restrict__ bD,
    float* __restrict__ S, size_t sbs, int Ld) {
  int L2 = Ld * 2;
  int out = blockIdx.x * 4 + (threadIdx.x >> 6);
  int lane = threadIdx.x & 63;
  int total = NBATCH * CKCH * L2;
  if (out >= total) return;
  int b = out / (CKCH * L2);
  int rem = out % (CKCH * L2);
  int o = rem / L2, t = rem % L2;
  float rA, mA, rD, mD;
  get_affine(stA, ntA, smA, rA, mA);
  get_affine(stD, ntD, 1, rD, mD);
  const float* Ab = A + (size_t)b * abs_;
  const float* Db = D + (size_t)b * dbs;
  float acc = 0.f;
  for (int j = 0; j < 8; ++j) {
    int i = lane + 64 * j;
    const float* wa = WA + ((size_t)o * CKCH + i) * 7;
    const float* wd = WD + ((size_t)o * CKCH + i) * 7;
    const float* ar = Ab + (size_t)i * Ld;
    const float* dr = Db + (size_t)i * Ld;
    #pragma unroll
    for (int f = 0; f < 7; ++f) {
      int p = t + f - 3;
      if (p >= 0 && p < L2) {
        int q = p >> 1;
        acc = fmaf(fmaf(ar[q], rA, mA), wa[f], acc);
        acc = fmaf(fmaf(dr[q], rD, mD), wd[f], acc);
      }
    }
  }
  #pragma unroll
  for (int off = 32; off > 0; off >>= 1) acc += __shfl_down(acc, off);
  if (lane == 0)
    S[(size_t)b * sbs + (size_t)o * L2 + t] = acc + bA[o] + bD[o];
}

__global__ __launch_bounds__(256) void k_stats(const float* __restrict__ S, size_t sbs,
                                               double* __restrict__ st, long n, int nb) {
  float s = 0.f, s2 = 0.f;
  for (long idx = blockIdx.x * 256L + threadIdx.x; idx < n; idx += (long)gridDim.x * 256) {
    int b = (int)(idx / nb);
    long rp = idx % nb;
    float v = S[(size_t)b * sbs + rp];
    s += v; s2 += v * v;
  }
  block_stats<256>(s, s2, st, threadIdx.x);
}

// ---------------------------------------------------------------------------
// Twiddle table: tw[p] = (cos, sin)(2*pi*p/1024). One table serves all levels.
// ---------------------------------------------------------------------------
__global__ void k_mktw(float2* tw) {
  int p = blockIdx.x * 256 + threadIdx.x;
  if (p < 1024) {
    float s, c;
    sincosf(TWO_PI_F * (float)p * (1.0f / 1024.0f), &s, &c);
    tw[p] = make_float2(c, s);
  }
}

// ---------------------------------------------------------------------------
// Truncated DFT of scrambled view xr[k,m]=H_flat[m*512+k]; LDS-tiled.
// block (64 k, 4 x)
// ---------------------------------------------------------------------------
__global__ __launch_bounds__(256) void k_dft2(const float* __restrict__ H, size_t hbs,
                                              const float2* __restrict__ tw,
                                              float* __restrict__ xfr, float* __restrict__ xfi,
                                              int Lh, int l) {
  __shared__ float Hs[64][65];
  __shared__ float2 tws[1024];
  int tx = threadIdx.x, ty = threadIdx.y;
  int tid = ty * 64 + tx;
  for (int idx = tid; idx < 1024; idx += 256) tws[idx] = tw[idx];
  int k = blockIdx.x * 64 + tx;
  int x = blockIdx.y * 4 + ty;
  int b = blockIdx.z;
  const float* Hb = H + (size_t)b * hbs;
  int step = 1024 / Lh;
  int dp = (x * step) & 1023;
  float ar = 0.f, ai = 0.f;
  for (int m0 = 0; m0 < Lh; m0 += 64) {
    int mc = min(64, Lh - m0);
    __syncthreads();
    for (int idx = tid; idx < mc * 64; idx += 256) {
      int mm = idx >> 6, kk = idx & 63;
      Hs[mm][kk] = Hb[(size_t)(m0 + mm) * CKCH + blockIdx.x * 64 + kk];
    }
    __syncthreads();
    int p = (int)(((long)dp * m0) & 1023);
    for (int mm = 0; mm < mc; ++mm) {
      float2 w = tws[p];
      float v = Hs[mm][tx];
      ar = fmaf(v, w.x, ar);
      ai = fmaf(v, -w.y, ai);
      p = (p + dp) & 1023;
    }
  }
  if (x < l) {
    xfr[((size_t)b * CKCH + k) * 16 + x] = ar;
    xfi[((size_t)b * CKCH + k) * 16 + x] = ai;
  }
}

// ---------------------------------------------------------------------------
// Per-mode complex channel mixing
// ---------------------------------------------------------------------------
__global__ __launch_bounds__(256) void k_einsum(const float* __restrict__ xfr,
                                                const float* __restrict__ xfi,
                                                const float* __restrict__ wr,
                                                const float* __restrict__ wi,
                                                float* __restrict__ outr,
                                                float* __restrict__ outi, int l) {
  int gid = blockIdx.x * 256 + threadIdx.x;
  int o = gid >> 4, x = gid & 15;
  if (x >= l) return;
  float ar[NBATCH] = {0, 0, 0, 0}, ai[NBATCH] = {0, 0, 0, 0};
  for (int i = 0; i < CKCH; ++i) {
    float wre = wr[((size_t)i * CKCH + o) * 16 + x];
    float wim = wi[((size_t)i * CKCH + o) * 16 + x];
    #pragma unroll
    for (int b = 0; b < NBATCH; ++b) {
      float xre = xfr[((size_t)b * CKCH + i) * 16 + x];
      float xim = xfi[((size_t)b * CKCH + i) * 16 + x];
      ar[b] += xre * wre - xim * wim;
      ai[b] += xre * wim + xim * wre;
    }
  }
  #pragma unroll
  for (int b = 0; b < NBATCH; ++b) {
    outr[((size_t)b * CKCH + o) * 16 + x] = ar[b];
    outi[((size_t)b * CKCH + o) * 16 + x] = ai[b];
  }
}

// ---------------------------------------------------------------------------
// Truncated irfft + [t*512+k] write + global stats. 4 t's per block row.
// ---------------------------------------------------------------------------
__global__ __launch_bounds__(256) void k_irfft2(const float* __restrict__ outr,
                                                const float* __restrict__ outi,
                                                const float2* __restrict__ tw,
                                                float* __restrict__ Y, size_t ybs,
                                                double* __restrict__ st, int Lh, int l) {
  int k = blockIdx.x * 256 + threadIdx.x;
  int b = blockIdx.z;
  int t0 = blockIdx.y * 4;
  int step = 1024 / Lh;
  float invL = 1.0f / (float)Lh;
  float acc[4] = {0.f, 0.f, 0.f, 0.f};
  size_t base = ((size_t)b * CKCH + k) * 16;
  for (int x = 0; x < l; ++x) {
    float re = outr[base + x], im = outi[base + x];
    float coef = (x == 0 || 2 * x == Lh) ? 1.f : 2.f;
    float cre = coef * re, cim = coef * im;
    #pragma unroll
    for (int tt = 0; tt < 4; ++tt) {
      int t = t0 + tt;
      int p = (x * t * step) & 1023;
      float2 w = tw[p];
      acc[tt] = fmaf(cre, w.x, fmaf(-cim, w.y, acc[tt]));
    }
  }
  float s = 0.f, s2 = 0.f;
  float* Yb = Y + (size_t)b * ybs;
  #pragma unroll
  for (int tt = 0; tt < 4; ++tt) {
    int t = t0 + tt;
    if (t < Lh) {
      float y = acc[tt] * invL;
      Yb[(size_t)t * CKCH + k] = y;
      s += y; s2 += y * y;
    }
  }
  block_stats<256>(s, s2, st, threadIdx.x);
}

// ---------------------------------------------------------------------------
// Between-block permute with fused norm + relu + 1/sqrt2
// ---------------------------------------------------------------------------
__global__ __launch_bounds__(256) void k_permute_relu(const float* __restrict__ in,
                                                      const double* __restrict__ st, long ntot,
                                                      float* __restrict__ out) {
  long idx = (long)blockIdx.x * 256 + threadIdx.x;
  const long total = (long)NBATCH * CKCH * NSEQ;
  if (idx >= total) return;
  float r, madj;
  get_affine(st, ntot, 0, r, madj);
  int b = (int)(idx / (CKCH * NSEQ));
  int rr = (int)(idx % (CKCH * NSEQ));
  int k = rr / NSEQ, t = rr % NSEQ;
  float v = in[(size_t)b * CKCH * NSEQ + (size_t)t * CKCH + k] * r;
  out[idx] = fmaxf(v, 0.f) * INV_SQRT2;
}

// ---------------------------------------------------------------------------
// Final L2 projection with fused norm + relu + 1/sqrt2
// ---------------------------------------------------------------------------
#define TT2 8
__global__ __launch_bounds__(256) void k_l2(const float* __restrict__ Vf,
                                            const double* __restrict__ st, long ntot,
                                            const float* __restrict__ w,
                                            const float* __restrict__ bias,
                                            float* __restrict__ out) {
  __shared__ float sh[TT2][CKCH];
  int b = blockIdx.z;
  int m0 = blockIdx.x * TT2;
  int tid = threadIdx.x;
  float r, madj;
  get_affine(st, ntot, 0, r, madj);
  for (int i = tid; i < TT2 * CKCH; i += 256) {
    int tt = i >> 9, k = i & 511;
    float v = Vf[(size_t)b * CKCH * NSEQ + (size_t)(m0 + tt) * CKCH + k] * r;
    sh[tt][k] = fmaxf(v, 0.f) * INV_SQRT2;
  }
  __syncthreads();
  int o = tid;
  float acc[TT2];
  #pragma unroll
  for (int tt = 0; tt < TT2; ++tt) acc[tt] = 0.f;
  const float* wo = w + (size_t)o * CKCH;
  for (int k = 0; k < CKCH; ++k) {
    float wv = wo[k];
    #pragma unroll
    for (int tt = 0; tt < TT2; ++tt) acc[tt] += sh[tt][k] * wv;
  }
  float bv = bias[o];
  #pragma unroll
  for (int tt = 0; tt < TT2; ++tt)
    out[((size_t)b * NSEQ + m0 + tt) * 256 + o] = acc[tt] + bv;
}

// ---------------------------------------------------------------------------
extern "C" void kernel_launch(void* const* d_in, const int* in_sizes, int n_in,
                              void* d_out, int out_size, void* d_ws, size_t ws_size,
                              hipStream_t stream) {
  const float* values  = (const float*)d_in[2];
  const float* L1w     = (const float*)d_in[4];
  const float* L1b     = (const float*)d_in[5];
  const float* L2w     = (const float*)d_in[6];
  const float* L2b     = (const float*)d_in[7];
  const float* ec_hp_w = (const float*)d_in[8];
  const float* ec_hp_b = (const float*)d_in[9];
  const float* ec_lp_w = (const float*)d_in[10];
  const float* ec_lp_b = (const float*)d_in[11];
  const float* hp_wr   = (const float*)d_in[12];
  const float* hp_wi   = (const float*)d_in[13];
  const float* lp_wr   = (const float*)d_in[14];
  const float* lp_wi   = (const float*)d_in[15];
  const float* rc_lp_w = (const float*)d_in[16];
  const float* rc_lp_b = (const float*)d_in[17];
  const float* rc_hp_w = (const float*)d_in[18];
  const float* rc_hp_b = (const float*)d_in[19];

  double* stats = (double*)d_ws;
  float2* tw = (float2*)((char*)d_ws + 2048);
  float* base = (float*)((char*)d_ws + 12288);
  const size_t AB = (size_t)CKCH * NSEQ;
  const size_t CB = (size_t)CKCH * CKCH;
  const size_t XB = (size_t)CKCH * 16;
  const size_t DB = (size_t)CKCH * 1023;

  float* A   = base;
  float* Bb  = A   + (size_t)NBATCH * AB;
  float* C1  = Bb  + (size_t)NBATCH * AB;
  float* XFr = C1  + (size_t)NBATCH * CB;
  float* XFi = XFr + (size_t)NBATCH * XB;
  float* OMr = XFi + (size_t)NBATCH * XB;
  float* OMi = OMr + (size_t)NBATCH * XB;
  float* Dd  = OMi + (size_t)NBATCH * XB;

  (void)hipMemsetAsync(stats, 0, 2048, stream);
  k_mktw<<<dim3(4), 256, 0, stream>>>(tw);
  k_l1t<<<dim3(NSEQ / TT1, 1, NBATCH), 256, 0, stream>>>(values, L1w, L1b, A);

  auto conv2 = [&](const float* Xin, const double* stIn, long ntIn, int smIn,
                   const float* Wc, const float* bc, float* Yout, size_t ybs, int L) {
    int Lh = L >> 1;
    if (Lh >= 64)
      k_conv2_t<64><<<dim3(Lh / 64, 16, NBATCH), dim3(16, 8), 0, stream>>>(
          Xin, AB, stIn, ntIn, smIn, Wc, bc, Yout, ybs, L);
    else if (Lh == 32)
      k_conv2_t<32><<<dim3(1, 16, NBATCH), dim3(8, 8), 0, stream>>>(
          Xin, AB, stIn, ntIn, smIn, Wc, bc, Yout, ybs, L);
    else if (Lh == 16)
      k_conv2_t<16><<<dim3(1, 16, NBATCH), dim3(4, 8), 0, stream>>>(
          Xin, AB, stIn, ntIn, smIn, Wc, bc, Yout, ybs, L);
    else {
      int total = NBATCH * CKCH * Lh;
      k_conv2_w<<<dim3((total + 3) / 4), 256, 0, stream>>>(
          Xin, AB, stIn, ntIn, smIn, Wc, bc, Yout, ybs, L);
    }
  };

  float* cur = A;
  float* nxt = Bb;

  for (int blk = 0; blk < 2; ++blk) {
    const float* ehw = ec_hp_w + (size_t)blk * CKCH * CKCH * 7;
    const float* ehb = ec_hp_b + (size_t)blk * CKCH;
    const float* elw = ec_lp_w + (size_t)blk * CKCH * CKCH * 7;
    const float* elb = ec_lp_b + (size_t)blk * CKCH;
    const float* hwr = hp_wr + (size_t)blk * CKCH * CKCH * 16;
    const float* hwi = hp_wi + (size_t)blk * CKCH * CKCH * 16;
    const float* lwr = lp_wr + (size_t)blk * CKCH * CKCH * 16;
    const float* lwi = lp_wi + (size_t)blk * CKCH * CKCH * 16;
    const float* rlw = rc_lp_w + (size_t)blk * CKCH * CKCH * 7;
    const float* rlb = rc_lp_b + (size_t)blk * CKCH;
    const float* rhw = rc_hp_w + (size_t)blk * CKCH * CKCH * 7;
    const float* rhb = rc_hp_b + (size_t)blk * CKCH;
    int sbase = blk * 30;

    int L = NSEQ;
    size_t doff = 0;
    for (int lvl = 0; lvl < NLEV; ++lvl) {
      int Lh = L >> 1;
      int l = (Lh / 2 + 1 < 16) ? (Lh / 2 + 1) : 16;
      const double* stIn = (lvl == 0) ? nullptr : stats + 2 * (sbase + 2 * (lvl - 1) + 1);
      long ntIn = 4L * CKCH * (NSEQ >> lvl);
      dim3 dgrid(CKCH / 64, (l + 3) / 4, NBATCH), dblk(64, 4);
      dim3 igrid(CKCH / 256, (Lh + 3) / 4, NBATCH);

      // high-pass branch -> detail buffer
      conv2(cur, stIn, ntIn, 1, ehw, ehb, C1, CB, L);
      k_dft2<<<dgrid, dblk, 0, stream>>>(C1, CB, tw, XFr, XFi, Lh, l);
      k_einsum<<<dim3(CKCH * 16 / 256), 256, 0, stream>>>(XFr, XFi, hwr, hwi, OMr, OMi, l);
      k_irfft2<<<igrid, 256, 0, stream>>>(OMr, OMi, tw, Dd + doff, DB,
                                          stats + 2 * (sbase + 2 * lvl), Lh, l);
      // low-pass branch -> next approximation
      conv2(cur, stIn, ntIn, 1, elw, elb, C1, CB, L);
      k_dft2<<<dgrid, dblk, 0, stream>>>(C1, CB, tw, XFr, XFi, Lh, l);
      k_einsum<<<dim3(CKCH * 16 / 256), 256, 0, stream>>>(XFr, XFi, lwr, lwi, OMr, OMi, l);
      k_irfft2<<<igrid, 256, 0, stream>>>(OMr, OMi, tw, nxt, AB,
                                          stats + 2 * (sbase + 2 * lvl + 1), Lh, l);
      float* tmp = cur; cur = nxt; nxt = tmp;
      doff += (size_t)CKCH * Lh;
      L = Lh;
    }

    int Ld = 1;
    for (int lv = 0; lv < NLEV; ++lv) {
      int lvlD = NLEV - 1 - lv;
      size_t od = (size_t)CKCH * (size_t)(1024 - (1024 >> lvlD));
      int L2 = 2 * Ld;
      const double* stA = (lv == 0) ? stats + 2 * (sbase + 19)
                                    : stats + 2 * (sbase + 20 + lv - 1);
      int smA = (lv == 0) ? 1 : 0;
      long ntA = 4L * CKCH * Ld;
      const double* stD = stats + 2 * (sbase + 2 * lvlD);
      long ntD = 4L * CKCH * Ld;
      double* stOut = stats + 2 * (sbase + 20 + lv);

      if (L2 >= 64)
        k_conv_rec_t<64><<<dim3(L2 / 64, 16, NBATCH), dim3(16, 8), 0, stream>>>(
            cur, AB, stA, ntA, smA, Dd + od, DB, stD, ntD,
            rlw, rlb, rhw, rhb, nxt, AB, stOut, Ld);
      else if (L2 == 32)
        k_conv_rec_t<32><<<dim3(1, 16, NBATCH), dim3(8, 8), 0, stream>>>(
            cur, AB, stA, ntA, smA, Dd + od, DB, stD, ntD,
            rlw, rlb, rhw, rhb, nxt, AB, stOut, Ld);
      else if (L2 == 16)
        k_conv_rec_t<16><<<dim3(1, 16, NBATCH), dim3(4, 8), 0, stream>>>(
            cur, AB, stA, ntA, smA, Dd + od, DB, stD, ntD,
            rlw, rlb, rhw, rhb, nxt, AB, stOut, Ld);
      else {
        int total = NBATCH * CKCH * L2;
        k_conv_rec_w<<<dim3((total + 3) / 4), 256, 0, stream>>>(
            cur, AB, stA, ntA, smA, Dd + od, DB, stD, ntD,
            rlw, rlb, rhw, rhb, nxt, AB, Ld);
        long n = (long)NBATCH * CKCH * L2;
        k_stats<<<dim3((unsigned)((n + 255) / 256)), 256, 0, stream>>>(
            nxt, AB, stOut, n, CKCH * L2);
      }
      float* tmp = cur; cur = nxt; nxt = tmp;
      Ld = L2;
    }

    if (blk == 0) {
      long tot = (long)NBATCH * CKCH * NSEQ;
      k_permute_relu<<<dim3((unsigned)((tot + 255) / 256)), 256, 0, stream>>>(
          cur, stats + 2 * (sbase + 29), tot, nxt);
      float* tmp = cur; cur = nxt; nxt = tmp;
    }
  }

  k_l2<<<dim3(NSEQ / TT2, 1, NBATCH), 256, 0, stream>>>(
      cur, stats + 2 * (30 + 29), (long)NBATCH * CKCH * NSEQ, L2w, L2b, (float*)d_out);
}

// Round 4
// 25795.694 us; speedup vs baseline: 2.1358x; 1.1150x over previous
//
#include <hip/hip_runtime.h>
#include <math.h>

#define CKCH 512
#define NLEV 10
#define NBATCH 4
#define NSEQ 1024
#define TWO_PI_F 6.2831853071795864769f
#define INV_SQRT2 0.70710678118654752440f
#define IC 8
#define EP 4   // einsum i-partitions

// ---------------------------------------------------------------------------
__device__ __forceinline__ void get_affine(const double* st, long ntot, int subMean,
                                           float& r, float& madj) {
  r = 1.f; madj = 0.f;
  if (!st) return;
  double s1 = st[0], s2 = st[1];
  double mean = s1 / (double)ntot;
  double var = (s2 - s1 * mean) / (double)(ntot - 1);
  double rs = 1.0 / sqrt(var);
  r = (float)rs;
  madj = subMean ? (float)(-mean * rs) : 0.f;
}

template<int NTHR>
__device__ __forceinline__ void block_stats(float s, float s2, double* st, int tid) {
  if constexpr (NTHR <= 64) {
    #pragma unroll
    for (int off = NTHR / 2; off > 0; off >>= 1) {
      s += __shfl_down(s, off);
      s2 += __shfl_down(s2, off);
    }
    if (tid == 0) { atomicAdd(st, (double)s); atomicAdd(st + 1, (double)s2); }
  } else {
    #pragma unroll
    for (int off = 32; off > 0; off >>= 1) {
      s += __shfl_down(s, off);
      s2 += __shfl_down(s2, off);
    }
    __shared__ float sh1[NTHR / 64], sh2[NTHR / 64];
    int w = tid >> 6;
    if ((tid & 63) == 0) { sh1[w] = s; sh2[w] = s2; }
    __syncthreads();
    if (tid == 0) {
      float a = 0.f, b = 0.f;
      #pragma unroll
      for (int i = 0; i < NTHR / 64; ++i) { a += sh1[i]; b += sh2[i]; }
      atomicAdd(st, (double)a); atomicAdd(st + 1, (double)b);
    }
  }
}

// ---------------------------------------------------------------------------
#define TT1 8
__global__ __launch_bounds__(256) void k_l1t(const float* __restrict__ vals,
                                             const float* __restrict__ w,
                                             const float* __restrict__ bias,
                                             float* __restrict__ out) {
  __shared__ float sh[TT1][256];
  int b = blockIdx.z;
  int t0 = blockIdx.x * TT1;
  int tid = threadIdx.x;
  for (int i = tid; i < TT1 * 256; i += 256) {
    int tt = i >> 8, d = i & 255;
    sh[tt][d] = vals[((size_t)(b * NSEQ + t0 + tt)) * 256 + d];
  }
  __syncthreads();
  for (int k = tid; k < CKCH; k += 256) {
    float acc[TT1];
    #pragma unroll
    for (int tt = 0; tt < TT1; ++tt) acc[tt] = 0.f;
    const float* wr = w + (size_t)k * 256;
    for (int d = 0; d < 256; ++d) {
      float wv = wr[d];
      #pragma unroll
      for (int tt = 0; tt < TT1; ++tt) acc[tt] += sh[tt][d] * wv;
    }
    float bv = bias[k];
    #pragma unroll
    for (int tt = 0; tt < TT1; ++tt)
      out[(size_t)b * CKCH * NSEQ + (size_t)k * NSEQ + (t0 + tt)] = acc[tt] + bv;
  }
}

// ---------------------------------------------------------------------------
// Tiled stride-2 conv (big levels), fused input affine. 4o x 4t per thread.
// ---------------------------------------------------------------------------
template<int TT>
__global__ __launch_bounds__((TT / 4) * 8) void k_conv2_t(
    const float* __restrict__ X, size_t xbs,
    const double* __restrict__ st, long ntot, int subMean,
    const float* __restrict__ W, const float* __restrict__ bias,
    float* __restrict__ Y, size_t ybs, int L) {
  constexpr int SP = 2 * TT + 8;
  constexpr int NTHR = (TT / 4) * 8;
  __shared__ float Xs[IC][SP];
  __shared__ float Ws[IC][32][8];
  int tx = threadIdx.x, ty = threadIdx.y;
  int tid = ty * (TT / 4) + tx;
  int b = blockIdx.z;
  int t0 = blockIdx.x * TT;
  int o0 = blockIdx.y * 32;
  int Lh = L >> 1;
  float r, madj;
  get_affine(st, ntot, subMean, r, madj);
  const float* Xb = X + (size_t)b * xbs;
  int pbase = 2 * t0 - 3;
  float acc[4][4];
  #pragma unroll
  for (int i = 0; i < 4; ++i)
    #pragma unroll
    for (int j = 0; j < 4; ++j) acc[i][j] = 0.f;

  for (int ic = 0; ic < CKCH / IC; ++ic) {
    int i0 = ic * IC;
    for (int idx = tid; idx < IC * (2 * TT + 6); idx += NTHR) {
      int ii = idx / (2 * TT + 6), pp = idx % (2 * TT + 6);
      int p = pbase + pp;
      float v = 0.f;
      if (p >= 0 && p < L) v = fmaf(Xb[(size_t)(i0 + ii) * L + p], r, madj);
      Xs[ii][pp] = v;
    }
    for (int idx = tid; idx < 32 * IC * 7; idx += NTHR) {
      int o = idx / (IC * 7);
      int rr = idx % (IC * 7);
      int ii = rr / 7, f = rr % 7;
      Ws[ii][o][f] = W[((size_t)(o0 + o) * CKCH + (i0 + ii)) * 7 + f];
    }
    __syncthreads();
    #pragma unroll
    for (int ii = 0; ii < IC; ++ii) {
      float xv[16];
      #pragma unroll
      for (int u = 0; u < 4; ++u)
        *(float4*)&xv[4 * u] = *(const float4*)&Xs[ii][8 * tx + 4 * u];
      #pragma unroll
      for (int oo = 0; oo < 4; ++oo) {
        float wv[8];
        *(float4*)&wv[0] = *(const float4*)&Ws[ii][ty + 8 * oo][0];
        *(float4*)&wv[4] = *(const float4*)&Ws[ii][ty + 8 * oo][4];
        #pragma unroll
        for (int tt = 0; tt < 4; ++tt)
          #pragma unroll
          for (int f = 0; f < 7; ++f)
            acc[oo][tt] = fmaf(xv[2 * tt + f], wv[f], acc[oo][tt]);
      }
    }
    __syncthreads();
  }
  float* Yb = Y + (size_t)b * ybs;
  #pragma unroll
  for (int oo = 0; oo < 4; ++oo) {
    int o = o0 + ty + 8 * oo;
    float bv = bias[o];
    float4 v = make_float4(acc[oo][0] + bv, acc[oo][1] + bv,
                           acc[oo][2] + bv, acc[oo][3] + bv);
    *(float4*)&Yb[(size_t)o * Lh + t0 + 4 * tx] = v;
  }
}

// wave-per-output variant for small levels (Lh <= 32): parallelism axis is
// (batch, out-channel, t) with the 512-ch reduction across the 64 lanes.
__global__ __launch_bounds__(256) void k_conv2_w(
    const float* __restrict__ X, size_t xbs,
    const double* __restrict__ st, long ntot, int subMean,
    const float* __restrict__ W, const float* __restrict__ bias,
    float* __restrict__ Y, size_t ybs, int L) {
  int Lh = L >> 1;
  int out = blockIdx.x * 4 + (threadIdx.x >> 6);
  int lane = threadIdx.x & 63;
  int total = NBATCH * CKCH * Lh;
  if (out >= total) return;
  int b = out / (CKCH * Lh);
  int rem = out % (CKCH * Lh);
  int o = rem / Lh, t = rem % Lh;
  float r, madj;
  get_affine(st, ntot, subMean, r, madj);
  const float* Xb = X + (size_t)b * xbs;
  const float* wo = W + (size_t)o * CKCH * 7;
  float acc = 0.f;
  for (int j = 0; j < 8; ++j) {
    int i = lane + 64 * j;
    const float* wr = wo + i * 7;
    const float* xr = Xb + (size_t)i * L;
    #pragma unroll
    for (int f = 0; f < 7; ++f) {
      int p = 2 * t + f - 3;
      if (p >= 0 && p < L) acc = fmaf(fmaf(xr[p], r, madj), wr[f], acc);
    }
  }
  #pragma unroll
  for (int off = 32; off > 0; off >>= 1) acc += __shfl_down(acc, off);
  if (lane == 0) Y[(size_t)b * ybs + (size_t)o * Lh + t] = acc + bias[o];
}

// ---------------------------------------------------------------------------
// Tiled reconstruction conv (big levels).
// ---------------------------------------------------------------------------
template<int TT>
__global__ __launch_bounds__((TT / 4) * 8) void k_conv_rec_t(
    const float* __restrict__ A, size_t abs_,
    const double* __restrict__ stA, long ntA, int smA,
    const float* __restrict__ D, size_t dbs,
    const double* __restrict__ stD, long ntD,
    const float* __restrict__ WA, const float* __restrict__ bA,
    const float* __restrict__ WD, const float* __restrict__ bD,
    float* __restrict__ S, size_t sbs,
    double* __restrict__ stOut, int Ld) {
  constexpr int QS = TT / 2 + 8;
  constexpr int NTHR = (TT / 4) * 8;
  __shared__ float As[IC][QS], Ds[IC][QS];
  __shared__ float Was[IC][32][8], Wds[IC][32][8];
  int tx = threadIdx.x, ty = threadIdx.y;
  int tid = ty * (TT / 4) + tx;
  int b = blockIdx.z;
  int t0 = blockIdx.x * TT;
  int o0 = blockIdx.y * 32;
  int L2 = Ld * 2;
  float rA, mA, rD, mD;
  get_affine(stA, ntA, smA, rA, mA);
  get_affine(stD, ntD, 1, rD, mD);
  const float* Ab = A + (size_t)b * abs_;
  const float* Db = D + (size_t)b * dbs;
  int q0 = t0 / 2 - 2;
  float acc[4][4];
  #pragma unroll
  for (int i = 0; i < 4; ++i)
    #pragma unroll
    for (int j = 0; j < 4; ++j) acc[i][j] = 0.f;

  for (int ic = 0; ic < CKCH / IC; ++ic) {
    int i0 = ic * IC;
    for (int idx = tid; idx < IC * (TT / 2 + 4); idx += NTHR) {
      int ii = idx / (TT / 2 + 4), qq = idx % (TT / 2 + 4);
      int q = q0 + qq;
      float va = 0.f, vd = 0.f;
      if (q >= 0 && q < Ld) {
        va = fmaf(Ab[(size_t)(i0 + ii) * Ld + q], rA, mA);
        vd = fmaf(Db[(size_t)(i0 + ii) * Ld + q], rD, mD);
      }
      As[ii][qq] = va;
      Ds[ii][qq] = vd;
    }
    for (int idx = tid; idx < 32 * IC * 7; idx += NTHR) {
      int o = idx / (IC * 7);
      int rr = idx % (IC * 7);
      int ii = rr / 7, f = rr % 7;
      size_t gw = ((size_t)(o0 + o) * CKCH + (i0 + ii)) * 7 + f;
      Was[ii][o][f] = WA[gw];
      Wds[ii][o][f] = WD[gw];
    }
    __syncthreads();
    #pragma unroll
    for (int ii = 0; ii < IC; ++ii) {
      float av[6], dv[6];
      #pragma unroll
      for (int u = 0; u < 3; ++u) {
        *(float2*)&av[2 * u] = *(const float2*)&As[ii][2 * tx + 2 * u];
        *(float2*)&dv[2 * u] = *(const float2*)&Ds[ii][2 * tx + 2 * u];
      }
      #pragma unroll
      for (int oo = 0; oo < 4; ++oo) {
        float wa[8], wd[8];
        *(float4*)&wa[0] = *(const float4*)&Was[ii][ty + 8 * oo][0];
        *(float4*)&wa[4] = *(const float4*)&Was[ii][ty + 8 * oo][4];
        *(float4*)&wd[0] = *(const float4*)&Wds[ii][ty + 8 * oo][0];
        *(float4*)&wd[4] = *(const float4*)&Wds[ii][ty + 8 * oo][4];
        #pragma unroll
        for (int tt = 0; tt < 4; ++tt) {
          #pragma unroll
          for (int f = 0; f < 7; ++f) {
            const int u = ((tt + f - 3) >> 1) + 2;
            acc[oo][tt] = fmaf(av[u], wa[f], acc[oo][tt]);
            acc[oo][tt] = fmaf(dv[u], wd[f], acc[oo][tt]);
          }
        }
      }
    }
    __syncthreads();
  }
  float s = 0.f, s2 = 0.f;
  float* Sb = S + (size_t)b * sbs;
  #pragma unroll
  for (int oo = 0; oo < 4; ++oo) {
    int o = o0 + ty + 8 * oo;
    float bv = bA[o] + bD[o];
    float4 v = make_float4(acc[oo][0] + bv, acc[oo][1] + bv,
                           acc[oo][2] + bv, acc[oo][3] + bv);
    *(float4*)&Sb[(size_t)o * L2 + t0 + 4 * tx] = v;
    s += v.x + v.y + v.z + v.w;
    s2 += v.x * v.x + v.y * v.y + v.z * v.z + v.w * v.w;
  }
  block_stats<NTHR>(s, s2, stOut, tid);
}

__global__ __launch_bounds__(256) void k_conv_rec_w(
    const float* __restrict__ A, size_t abs_,
    const double* __restrict__ stA, long ntA, int smA,
    const float* __restrict__ D, size_t dbs,
    const double* __restrict__ stD, long ntD,
    const float* __restrict__ WA, const float* __restrict__ bA,
    const float* __restrict__ WD, const float* __restrict__ bD,
    float* __restrict__ S, size_t sbs, int Ld) {
  int L2 = Ld * 2;
  int out = blockIdx.x * 4 + (threadIdx.x >> 6);
  int lane = threadIdx.x & 63;
  int total = NBATCH * CKCH * L2;
  if (out >= total) return;
  int b = out / (CKCH * L2);
  int rem = out % (CKCH * L2);
  int o = rem / L2, t = rem % L2;
  float rA, mA, rD, mD;
  get_affine(stA, ntA, smA, rA, mA);
  get_affine(stD, ntD, 1, rD, mD);
  const float* Ab = A + (size_t)b * abs_;
  const float* Db = D + (size_t)b * dbs;
  float acc = 0.f;
  for (int j = 0; j < 8; ++j) {
    int i = lane + 64 * j;
    const float* wa = WA + ((size_t)o * CKCH + i) * 7;
    const float* wd = WD + ((size_t)o * CKCH + i) * 7;
    const float* ar = Ab + (size_t)i * Ld;
    const float* dr = Db + (size_t)i * Ld;
    #pragma unroll
    for (int f = 0; f < 7; ++f) {
      int p = t + f - 3;
      if (p >= 0 && p < L2) {
        int q = p >> 1;
        acc = fmaf(fmaf(ar[q], rA, mA), wa[f], acc);
        acc = fmaf(fmaf(dr[q], rD, mD), wd[f], acc);
      }
    }
  }
  #pragma unroll
  for (int off = 32; off > 0; off >>= 1) acc += __shfl_down(acc, off);
  if (lane == 0)
    S[(size_t)b * sbs + (size_t)o * L2 + t] = acc + bA[o] + bD[o];
}

__global__ __launch_bounds__(256) void k_stats(const float* __restrict__ S, size_t sbs,
                                               double* __restrict__ st, long n, int nb) {
  float s = 0.f, s2 = 0.f;
  for (long idx = blockIdx.x * 256L + threadIdx.x; idx < n; idx += (long)gridDim.x * 256) {
    int b = (int)(idx / nb);
    long rp = idx % nb;
    float v = S[(size_t)b * sbs + rp];
    s += v; s2 += v * v;
  }
  block_stats<256>(s, s2, st, threadIdx.x);
}

// ---------------------------------------------------------------------------
__global__ void k_mktw(float2* tw) {
  int p = blockIdx.x * 256 + threadIdx.x;
  if (p < 1024) {
    float s, c;
    sincosf(TWO_PI_F * (float)p * (1.0f / 1024.0f), &s, &c);
    tw[p] = make_float2(c, s);
  }
}

// ---------------------------------------------------------------------------
__global__ __launch_bounds__(256) void k_dft2(const float* __restrict__ H, size_t hbs,
                                              const float2* __restrict__ tw,
                                              float* __restrict__ xfr, float* __restrict__ xfi,
                                              int Lh, int l) {
  __shared__ float Hs[64][65];
  __shared__ float2 tws[1024];
  int tx = threadIdx.x, ty = threadIdx.y;
  int tid = ty * 64 + tx;
  for (int idx = tid; idx < 1024; idx += 256) tws[idx] = tw[idx];
  int k = blockIdx.x * 64 + tx;
  int x = blockIdx.y * 4 + ty;
  int b = blockIdx.z;
  const float* Hb = H + (size_t)b * hbs;
  int step = 1024 / Lh;
  int dp = (x * step) & 1023;
  float ar = 0.f, ai = 0.f;
  for (int m0 = 0; m0 < Lh; m0 += 64) {
    int mc = min(64, Lh - m0);
    __syncthreads();
    for (int idx = tid; idx < mc * 64; idx += 256) {
      int mm = idx >> 6, kk = idx & 63;
      Hs[mm][kk] = Hb[(size_t)(m0 + mm) * CKCH + blockIdx.x * 64 + kk];
    }
    __syncthreads();
    int p = (int)(((long)dp * m0) & 1023);
    for (int mm = 0; mm < mc; ++mm) {
      float2 w = tws[p];
      float v = Hs[mm][tx];
      ar = fmaf(v, w.x, ar);
      ai = fmaf(v, -w.y, ai);
      p = (p + dp) & 1023;
    }
  }
  if (x < l) {
    xfr[((size_t)b * CKCH + k) * 16 + x] = ar;
    xfi[((size_t)b * CKCH + k) * 16 + x] = ai;
  }
}

// ---------------------------------------------------------------------------
// Per-mode complex channel mixing, i-reduction split over EP partial buffers
// (summed later by k_irfft2). grid (32, EP).
// ---------------------------------------------------------------------------
__global__ __launch_bounds__(256) void k_einsum(const float* __restrict__ xfr,
                                                const float* __restrict__ xfi,
                                                const float* __restrict__ wr,
                                                const float* __restrict__ wi,
                                                float* __restrict__ outr,
                                                float* __restrict__ outi, int l) {
  int gid = blockIdx.x * 256 + threadIdx.x;
  int o = gid >> 4, x = gid & 15;
  if (x >= l) return;
  int part = blockIdx.y;
  int i0 = part * (CKCH / EP);
  float ar[NBATCH] = {0, 0, 0, 0}, ai[NBATCH] = {0, 0, 0, 0};
  for (int i = i0; i < i0 + CKCH / EP; ++i) {
    float wre = wr[((size_t)i * CKCH + o) * 16 + x];
    float wim = wi[((size_t)i * CKCH + o) * 16 + x];
    #pragma unroll
    for (int b = 0; b < NBATCH; ++b) {
      float xre = xfr[((size_t)b * CKCH + i) * 16 + x];
      float xim = xfi[((size_t)b * CKCH + i) * 16 + x];
      ar[b] += xre * wre - xim * wim;
      ai[b] += xre * wim + xim * wre;
    }
  }
  size_t pb = (size_t)part * (NBATCH * CKCH * 16);
  #pragma unroll
  for (int b = 0; b < NBATCH; ++b) {
    outr[pb + ((size_t)b * CKCH + o) * 16 + x] = ar[b];
    outi[pb + ((size_t)b * CKCH + o) * 16 + x] = ai[b];
  }
}

// ---------------------------------------------------------------------------
// Truncated irfft (sums EP einsum partials) + [t*512+k] write + global stats.
// ---------------------------------------------------------------------------
__global__ __launch_bounds__(256) void k_irfft2(const float* __restrict__ outr,
                                                const float* __restrict__ outi,
                                                const float2* __restrict__ tw,
                                                float* __restrict__ Y, size_t ybs,
                                                double* __restrict__ st, int Lh, int l) {
  int k = blockIdx.x * 256 + threadIdx.x;
  int b = blockIdx.z;
  int t0 = blockIdx.y * 4;
  int step = 1024 / Lh;
  float invL = 1.0f / (float)Lh;
  float acc[4] = {0.f, 0.f, 0.f, 0.f};
  size_t base = ((size_t)b * CKCH + k) * 16;
  const size_t pstride = (size_t)NBATCH * CKCH * 16;
  for (int x = 0; x < l; ++x) {
    float re = 0.f, im = 0.f;
    #pragma unroll
    for (int p = 0; p < EP; ++p) {
      re += outr[p * pstride + base + x];
      im += outi[p * pstride + base + x];
    }
    float coef = (x == 0 || 2 * x == Lh) ? 1.f : 2.f;
    float cre = coef * re, cim = coef * im;
    #pragma unroll
    for (int tt = 0; tt < 4; ++tt) {
      int t = t0 + tt;
      int p = (x * t * step) & 1023;
      float2 w = tw[p];
      acc[tt] = fmaf(cre, w.x, fmaf(-cim, w.y, acc[tt]));
    }
  }
  float s = 0.f, s2 = 0.f;
  float* Yb = Y + (size_t)b * ybs;
  #pragma unroll
  for (int tt = 0; tt < 4; ++tt) {
    int t = t0 + tt;
    if (t < Lh) {
      float y = acc[tt] * invL;
      Yb[(size_t)t * CKCH + k] = y;
      s += y; s2 += y * y;
    }
  }
  block_stats<256>(s, s2, st, threadIdx.x);
}

// ---------------------------------------------------------------------------
__global__ __launch_bounds__(256) void k_permute_relu(const float* __restrict__ in,
                                                      const double* __restrict__ st, long ntot,
                                                      float* __restrict__ out) {
  long idx = (long)blockIdx.x * 256 + threadIdx.x;
  const long total = (long)NBATCH * CKCH * NSEQ;
  if (idx >= total) return;
  float r, madj;
  get_affine(st, ntot, 0, r, madj);
  int b = (int)(idx / (CKCH * NSEQ));
  int rr = (int)(idx % (CKCH * NSEQ));
  int k = rr / NSEQ, t = rr % NSEQ;
  float v = in[(size_t)b * CKCH * NSEQ + (size_t)t * CKCH + k] * r;
  out[idx] = fmaxf(v, 0.f) * INV_SQRT2;
}

// ---------------------------------------------------------------------------
#define TT2 8
__global__ __launch_bounds__(256) void k_l2(const float* __restrict__ Vf,
                                            const double* __restrict__ st, long ntot,
                                            const float* __restrict__ w,
                                            const float* __restrict__ bias,
                                            float* __restrict__ out) {
  __shared__ float sh[TT2][CKCH];
  int b = blockIdx.z;
  int m0 = blockIdx.x * TT2;
  int tid = threadIdx.x;
  float r, madj;
  get_affine(st, ntot, 0, r, madj);
  for (int i = tid; i < TT2 * CKCH; i += 256) {
    int tt = i >> 9, k = i & 511;
    float v = Vf[(size_t)b * CKCH * NSEQ + (size_t)(m0 + tt) * CKCH + k] * r;
    sh[tt][k] = fmaxf(v, 0.f) * INV_SQRT2;
  }
  __syncthreads();
  int o = tid;
  float acc[TT2];
  #pragma unroll
  for (int tt = 0; tt < TT2; ++tt) acc[tt] = 0.f;
  const float* wo = w + (size_t)o * CKCH;
  for (int k = 0; k < CKCH; ++k) {
    float wv = wo[k];
    #pragma unroll
    for (int tt = 0; tt < TT2; ++tt) acc[tt] += sh[tt][k] * wv;
  }
  float bv = bias[o];
  #pragma unroll
  for (int tt = 0; tt < TT2; ++tt)
    out[((size_t)b * NSEQ + m0 + tt) * 256 + o] = acc[tt] + bv;
}

// ---------------------------------------------------------------------------
extern "C" void kernel_launch(void* const* d_in, const int* in_sizes, int n_in,
                              void* d_out, int out_size, void* d_ws, size_t ws_size,
                              hipStream_t stream) {
  const float* values  = (const float*)d_in[2];
  const float* L1w     = (const float*)d_in[4];
  const float* L1b     = (const float*)d_in[5];
  const float* L2w     = (const float*)d_in[6];
  const float* L2b     = (const float*)d_in[7];
  const float* ec_hp_w = (const float*)d_in[8];
  const float* ec_hp_b = (const float*)d_in[9];
  const float* ec_lp_w = (const float*)d_in[10];
  const float* ec_lp_b = (const float*)d_in[11];
  const float* hp_wr   = (const float*)d_in[12];
  const float* hp_wi   = (const float*)d_in[13];
  const float* lp_wr   = (const float*)d_in[14];
  const float* lp_wi   = (const float*)d_in[15];
  const float* rc_lp_w = (const float*)d_in[16];
  const float* rc_lp_b = (const float*)d_in[17];
  const float* rc_hp_w = (const float*)d_in[18];
  const float* rc_hp_b = (const float*)d_in[19];

  double* stats = (double*)d_ws;
  float2* tw = (float2*)((char*)d_ws + 2048);
  float* base = (float*)((char*)d_ws + 12288);
  const size_t AB = (size_t)CKCH * NSEQ;
  const size_t CB = (size_t)CKCH * CKCH;
  const size_t XB = (size_t)CKCH * 16;
  const size_t DB = (size_t)CKCH * 1023;

  float* A   = base;
  float* Bb  = A   + (size_t)NBATCH * AB;
  float* C1  = Bb  + (size_t)NBATCH * AB;
  float* XFr = C1  + (size_t)NBATCH * CB;
  float* XFi = XFr + (size_t)NBATCH * XB;
  float* OMr = XFi + (size_t)NBATCH * XB;
  float* OMi = OMr + (size_t)NBATCH * XB * EP;
  float* Dd  = OMi + (size_t)NBATCH * XB * EP;

  (void)hipMemsetAsync(stats, 0, 2048, stream);
  k_mktw<<<dim3(4), 256, 0, stream>>>(tw);
  k_l1t<<<dim3(NSEQ / TT1, 1, NBATCH), 256, 0, stream>>>(values, L1w, L1b, A);

  auto conv2 = [&](const float* Xin, const double* stIn, long ntIn, int smIn,
                   const float* Wc, const float* bc, float* Yout, size_t ybs, int L) {
    int Lh = L >> 1;
    if (Lh >= 64)
      k_conv2_t<64><<<dim3(Lh / 64, 16, NBATCH), dim3(16, 8), 0, stream>>>(
          Xin, AB, stIn, ntIn, smIn, Wc, bc, Yout, ybs, L);
    else {
      int total = NBATCH * CKCH * Lh;
      k_conv2_w<<<dim3((total + 3) / 4), 256, 0, stream>>>(
          Xin, AB, stIn, ntIn, smIn, Wc, bc, Yout, ybs, L);
    }
  };

  float* cur = A;
  float* nxt = Bb;

  for (int blk = 0; blk < 2; ++blk) {
    const float* ehw = ec_hp_w + (size_t)blk * CKCH * CKCH * 7;
    const float* ehb = ec_hp_b + (size_t)blk * CKCH;
    const float* elw = ec_lp_w + (size_t)blk * CKCH * CKCH * 7;
    const float* elb = ec_lp_b + (size_t)blk * CKCH;
    const float* hwr = hp_wr + (size_t)blk * CKCH * CKCH * 16;
    const float* hwi = hp_wi + (size_t)blk * CKCH * CKCH * 16;
    const float* lwr = lp_wr + (size_t)blk * CKCH * CKCH * 16;
    const float* lwi = lp_wi + (size_t)blk * CKCH * CKCH * 16;
    const float* rlw = rc_lp_w + (size_t)blk * CKCH * CKCH * 7;
    const float* rlb = rc_lp_b + (size_t)blk * CKCH;
    const float* rhw = rc_hp_w + (size_t)blk * CKCH * CKCH * 7;
    const float* rhb = rc_hp_b + (size_t)blk * CKCH;
    int sbase = blk * 30;

    int L = NSEQ;
    size_t doff = 0;
    for (int lvl = 0; lvl < NLEV; ++lvl) {
      int Lh = L >> 1;
      int l = (Lh / 2 + 1 < 16) ? (Lh / 2 + 1) : 16;
      const double* stIn = (lvl == 0) ? nullptr : stats + 2 * (sbase + 2 * (lvl - 1) + 1);
      long ntIn = 4L * CKCH * (NSEQ >> lvl);
      dim3 dgrid(CKCH / 64, (l + 3) / 4, NBATCH), dblk(64, 4);
      dim3 egrid(CKCH * 16 / 256, EP);
      dim3 igrid(CKCH / 256, (Lh + 3) / 4, NBATCH);

      // high-pass branch -> detail buffer
      conv2(cur, stIn, ntIn, 1, ehw, ehb, C1, CB, L);
      k_dft2<<<dgrid, dblk, 0, stream>>>(C1, CB, tw, XFr, XFi, Lh, l);
      k_einsum<<<egrid, 256, 0, stream>>>(XFr, XFi, hwr, hwi, OMr, OMi, l);
      k_irfft2<<<igrid, 256, 0, stream>>>(OMr, OMi, tw, Dd + doff, DB,
                                          stats + 2 * (sbase + 2 * lvl), Lh, l);
      // low-pass branch -> next approximation
      conv2(cur, stIn, ntIn, 1, elw, elb, C1, CB, L);
      k_dft2<<<dgrid, dblk, 0, stream>>>(C1, CB, tw, XFr, XFi, Lh, l);
      k_einsum<<<egrid, 256, 0, stream>>>(XFr, XFi, lwr, lwi, OMr, OMi, l);
      k_irfft2<<<igrid, 256, 0, stream>>>(OMr, OMi, tw, nxt, AB,
                                          stats + 2 * (sbase + 2 * lvl + 1), Lh, l);
      float* tmp = cur; cur = nxt; nxt = tmp;
      doff += (size_t)CKCH * Lh;
      L = Lh;
    }

    int Ld = 1;
    for (int lv = 0; lv < NLEV; ++lv) {
      int lvlD = NLEV - 1 - lv;
      size_t od = (size_t)CKCH * (size_t)(1024 - (1024 >> lvlD));
      int L2 = 2 * Ld;
      const double* stA = (lv == 0) ? stats + 2 * (sbase + 19)
                                    : stats + 2 * (sbase + 20 + lv - 1);
      int smA = (lv == 0) ? 1 : 0;
      long ntA = 4L * CKCH * Ld;
      const double* stD = stats + 2 * (sbase + 2 * lvlD);
      long ntD = 4L * CKCH * Ld;
      double* stOut = stats + 2 * (sbase + 20 + lv);

      if (L2 >= 64) {
        k_conv_rec_t<64><<<dim3(L2 / 64, 16, NBATCH), dim3(16, 8), 0, stream>>>(
            cur, AB, stA, ntA, smA, Dd + od, DB, stD, ntD,
            rlw, rlb, rhw, rhb, nxt, AB, stOut, Ld);
      } else {
        int total = NBATCH * CKCH * L2;
        k_conv_rec_w<<<dim3((total + 3) / 4), 256, 0, stream>>>(
            cur, AB, stA, ntA, smA, Dd + od, DB, stD, ntD,
            rlw, rlb, rhw, rhb, nxt, AB, Ld);
        long n = (long)NBATCH * CKCH * L2;
        k_stats<<<dim3((unsigned)((n + 255) / 256)), 256, 0, stream>>>(
            nxt, AB, stOut, n, CKCH * L2);
      }
      float* tmp = cur; cur = nxt; nxt = tmp;
      Ld = L2;
    }

    if (blk == 0) {
      long tot = (long)NBATCH * CKCH * NSEQ;
      k_permute_relu<<<dim3((unsigned)((tot + 255) / 256)), 256, 0, stream>>>(
          cur, stats + 2 * (sbase + 29), tot, nxt);
      float* tmp = cur; cur = nxt; nxt = tmp;
    }
  }

  k_l2<<<dim3(NSEQ / TT2, 1, NBATCH), 256, 0, stream>>>(
      cur, stats + 2 * (30 + 29), (long)NBATCH * CKCH * NSEQ, L2w, L2b, (float*)d_out);
}